// Round 8
// baseline (557.400 us; speedup 1.0000x reference)
//
#include <hip/hip_runtime.h>
#include <hip/hip_bf16.h>

typedef __attribute__((ext_vector_type(8))) short bf16x8;
typedef __attribute__((ext_vector_type(4))) float f32x4;

// ---------------- helpers ----------------

__device__ __forceinline__ ushort f2bf(float f) {
    unsigned int b = __float_as_uint(f);
    unsigned int r = (b + 0x7fffu + ((b >> 16) & 1u)) >> 16;  // RNE
    return (ushort)r;
}
__device__ __forceinline__ float bflo(uint v) { return __uint_as_float(v << 16); }
__device__ __forceinline__ float bfhi(uint v) { return __uint_as_float(v & 0xffff0000u); }

// ---------------- prep: zero cnt + transpose-cast both weights ----------------

__global__ __launch_bounds__(256) void prep_kernel(const float* __restrict__ W1, ushort* __restrict__ W1t,
                                                   const float* __restrict__ W2, ushort* __restrict__ W2t,
                                                   int* __restrict__ cnt, int Nn, int zb) {
    int b = blockIdx.x, t = threadIdx.x;
    if (b < zb) {
        int i = b * 256 + t;
        if (i < Nn) cnt[i] = 0;
    } else if (b < zb + 128) {
        int i = (b - zb) * 256 + t;            // W1t[n][k], n in [0,256), k in [0,128)
        int n = i >> 7, k = i & 127;
        W1t[i] = f2bf(W1[(size_t)k * 256 + n]);
    } else {
        int i = (b - zb - 128) * 256 + t;      // W2t[n][k], n in [0,128), k in [0,256)
        int n = i >> 8, k = i & 255;
        W2t[i] = f2bf(W2[(size_t)k * 128 + n]);
    }
}

// ---------------- CSR build ----------------

// 1 edge/thread: maximize waves in flight (atomic throughput ~ resident waves)
__global__ void count_kernel(const int* __restrict__ dst, int* __restrict__ cnt,
                             int* __restrict__ rank, int E) {
    int e = blockIdx.x * blockDim.x + threadIdx.x;
    if (e < E) rank[e] = atomicAdd(&cnt[dst[e]], 1);
}

__global__ __launch_bounds__(1024) void scan_part(const int* __restrict__ cnt,
                                                  int* __restrict__ bsum, int Nn) {
    int i = blockIdx.x * 1024 + threadIdx.x;
    int v = (i < Nn) ? cnt[i] : 0;
#pragma unroll
    for (int d = 1; d < 64; d <<= 1) v += __shfl_xor(v, d, 64);
    __shared__ int wsums[16];
    if ((threadIdx.x & 63) == 0) wsums[threadIdx.x >> 6] = v;
    __syncthreads();
    if (threadIdx.x == 0) {
        int s = 0;
        for (int w = 0; w < 16; ++w) s += wsums[w];
        bsum[blockIdx.x] = s;
    }
}

// parallel exclusive scan over NB<=128 block sums (1 block, 128 threads)
__global__ __launch_bounds__(128) void scan_top(int* __restrict__ bsum, int NB) {
    int i = threadIdx.x;
    int v = (i < NB) ? bsum[i] : 0;
    int x = v;
#pragma unroll
    for (int d = 1; d < 64; d <<= 1) {
        int y = __shfl_up(x, d, 64);
        if ((i & 63) >= d) x += y;
    }
    __shared__ int w0;
    if (i == 63) w0 = x;
    __syncthreads();
    if (i >= 64) x += w0;
    if (i < NB) bsum[i] = x - v;
}

__global__ __launch_bounds__(1024) void scan_final(const int* __restrict__ cnt,
                                                   const int* __restrict__ bpre,
                                                   int* __restrict__ offs,
                                                   float* __restrict__ dis, int Nn, int E) {
    int i = blockIdx.x * 1024 + threadIdx.x;
    int v = (i < Nn) ? cnt[i] : 0;
    int lane = threadIdx.x & 63, wid = threadIdx.x >> 6;
    int x = v;
#pragma unroll
    for (int d = 1; d < 64; d <<= 1) {
        int y = __shfl_up(x, d, 64);
        if (lane >= d) x += y;
    }
    __shared__ int wsum[16];
    __shared__ int wpre[16];
    if (lane == 63) wsum[wid] = x;
    __syncthreads();
    if (threadIdx.x == 0) {
        int run = 0;
        for (int w = 0; w < 16; ++w) { wpre[w] = run; run += wsum[w]; }
    }
    __syncthreads();
    int excl = x - v + wpre[wid] + bpre[blockIdx.x];
    if (i < Nn) {
        offs[i] = excl;
        dis[i] = rsqrtf((float)v + 1.0f);
    }
    if (blockIdx.x == 0 && threadIdx.x == 0) offs[Nn] = E;
}

// ---------------- fused fill (2-wide, atomic-free) + cast_scale ----------------
// blocks [0,FB): fill; [FB,FB+CB): tbl[s][c] = bf16(dis[s]*emb[s][c])

__global__ void fill_cast_kernel(const int* __restrict__ src, const int* __restrict__ dst,
                                 const int* __restrict__ rank, const int* __restrict__ offs,
                                 int* __restrict__ rec, int E,
                                 const float4* __restrict__ emb, const float* __restrict__ dis,
                                 ushort4* __restrict__ tbl, int n4, int FB, int CB) {
    if ((int)blockIdx.x < FB) {
        int i = blockIdx.x * 256 + threadIdx.x;
        int e = i * 2;
        if (e + 1 < E) {
            int d0 = dst[e], d1 = dst[e + 1];
            int s0 = src[e], s1 = src[e + 1];
            int r0 = rank[e], r1 = rank[e + 1];
            int o0 = offs[d0], o1 = offs[d1];
            rec[o0 + r0] = s0;
            rec[o1 + r1] = s1;
        } else {
            for (; e < E; ++e) rec[offs[dst[e]] + rank[e]] = src[e];
        }
    } else {
        int stride = CB * 256;
        for (int i = ((int)blockIdx.x - FB) * 256 + (int)threadIdx.x; i < n4; i += stride) {
            float s = dis[i >> 5];
            float4 v = emb[i];
            ushort4 o;
            o.x = f2bf(v.x * s); o.y = f2bf(v.y * s); o.z = f2bf(v.z * s); o.w = f2bf(v.w * s);
            tbl[i] = o;
        }
    }
}

// ---------------- pass-sliced aggregation over 128 bf16 cols (pre-scaled table) ----------------
// tbl[s] = dis[s]*x[s] (bf16). out = dn * (tbl[gw] + sum_e tbl[rec[e]])  (+bias)
// 8 column-passes of 8 uints (16 bf16 cols): per pass the gather slice is
// Nn*32B = 3.2MB -> fits a 4MB per-XCD L2. Blocks are pass-major so co-resident
// blocks share the slice. 8-lane group per node: lane owns uint c=tid&7 of the
// slice; 8 edges in flight per lane per iteration.

template <bool BIAS, bool BF16OUT>
__global__ __launch_bounds__(256) void agg_sliced(const uint* __restrict__ tbl,   // [Nn][64]
                                                  const int* __restrict__ offs,
                                                  const int* __restrict__ rec,    // src per edge
                                                  const float* __restrict__ dis,
                                                  const float* __restrict__ bias,
                                                  void* __restrict__ outp,
                                                  int Nn, int npb) {
    int pass = (int)blockIdx.x / npb;
    int nb = (int)blockIdx.x % npb;
    int grp = threadIdx.x >> 3;            // 0..31, one node per 8-lane group
    int gw = nb * 32 + grp;
    if (gw >= Nn) return;
    uint c = threadIdx.x & 7u;
    uint off = (uint)pass * 8u + c;        // uint index within row
    float dn = dis[gw];
    int e0 = offs[gw], e1 = offs[gw + 1];
    uint sv = tbl[(uint)gw * 64u + off];   // self term
    float ax = bflo(sv), ay = bfhi(sv);

    for (int base = e0; base < e1; base += 8) {
        uint idx[8];
#pragma unroll
        for (int j = 0; j < 8; ++j) {
            int e = base + j;
            idx[j] = (uint)rec[e < e1 ? e : e1 - 1];
        }
        uint vv[8];
#pragma unroll
        for (int j = 0; j < 8; ++j) vv[j] = tbl[idx[j] * 64u + off];
#pragma unroll
        for (int j = 0; j < 8; ++j) {
            uint v = (base + j < e1) ? vv[j] : 0u;
            ax += bflo(v);
            ay += bfhi(v);
        }
    }

    ax *= dn; ay *= dn;
    if (BIAS) {
        float2 bv = reinterpret_cast<const float2*>(bias)[off];
        ax += bv.x; ay += bv.y;
    }
    if (BF16OUT) {
        reinterpret_cast<uint*>(outp)[(uint)gw * 64u + off] =
            (uint)f2bf(ax) | ((uint)f2bf(ay) << 16);
    } else {
        float2 o; o.x = ax; o.y = ay;
        reinterpret_cast<float2*>(outp)[(uint)gw * 64u + off] = o;
    }
}

// ---------------- fused MFMA GEMM: x = L2norm(A@W1 + b1); tbl2 = dis * (x@W2) ----------------
// A [M][128] bf16 (agg1 out), W1t [256][128] bf16, W2t [128][256] bf16.
// block = 4 waves, 64-row tile. All 32 stage-1 fragment loads hoisted (single
// latency window); W2 fragment loads issued under the stage-1 epilogue.
// __launch_bounds__(256,2): cap 256 VGPR so all fragments stay in flight.
// mfma_f32_16x16x32_bf16 C/D layout: col=lane&15, row=(lane>>4)*4+reg  [measured m89].

__global__ __launch_bounds__(256, 2) void fused_gemm(const ushort* __restrict__ A,
                                                     const ushort* __restrict__ W1t,
                                                     const float* __restrict__ bias1,
                                                     const ushort* __restrict__ W2t,
                                                     const float* __restrict__ dsc,
                                                     ushort* __restrict__ out2, int M) {
    __shared__ ushort xt[64 * 256];   // 32KB x-tile, elem ^= (row&7)<<3 swizzle
    __shared__ float ssl[4][64];
    int lane = threadIdx.x & 63, wid = threadIdx.x >> 6;
    int m0 = blockIdx.x * 64;
    int koff = (lane >> 4) * 8;

    // ---- stage 1: gemm1 K=128 -> N=256 ----
    bf16x8 a[4][4], b1f[4][4];
#pragma unroll
    for (int ms = 0; ms < 4; ++ms) {
        int r = m0 + ms * 16 + (lane & 15);
        if (r >= M) r = M - 1;
        const bf16x8* p = reinterpret_cast<const bf16x8*>(A + (size_t)r * 128 + koff);
#pragma unroll
        for (int ks = 0; ks < 4; ++ks) a[ms][ks] = p[ks * 4];
    }
#pragma unroll
    for (int ns = 0; ns < 4; ++ns) {
        int c = wid * 64 + ns * 16 + (lane & 15);
        const bf16x8* p = reinterpret_cast<const bf16x8*>(W1t + (size_t)c * 128 + koff);
#pragma unroll
        for (int ks = 0; ks < 4; ++ks) b1f[ns][ks] = p[ks * 4];
    }

    f32x4 acc[4][4];
#pragma unroll
    for (int ms = 0; ms < 4; ++ms)
#pragma unroll
        for (int ns = 0; ns < 4; ++ns) acc[ms][ns] = (f32x4){0.f, 0.f, 0.f, 0.f};
#pragma unroll
    for (int ks = 0; ks < 4; ++ks)
#pragma unroll
        for (int ms = 0; ms < 4; ++ms)
#pragma unroll
            for (int ns = 0; ns < 4; ++ns)
                acc[ms][ns] = __builtin_amdgcn_mfma_f32_16x16x32_bf16(a[ms][ks], b1f[ns][ks], acc[ms][ns], 0, 0, 0);

    // issue W2 fragment loads now: latency hides under the epilogue below
    bf16x8 b2f[2][8];
#pragma unroll
    for (int ns = 0; ns < 2; ++ns) {
        int c = wid * 32 + ns * 16 + (lane & 15);
        const bf16x8* p = reinterpret_cast<const bf16x8*>(W2t + (size_t)c * 256 + koff);
#pragma unroll
        for (int ks = 0; ks < 8; ++ks) b2f[ns][ks] = p[ks * 4];
    }

    // bias + row sum-of-squares
    float bv[4];
#pragma unroll
    for (int ns = 0; ns < 4; ++ns) bv[ns] = bias1[wid * 64 + ns * 16 + (lane & 15)];
    float ps[4][4];
#pragma unroll
    for (int ms = 0; ms < 4; ++ms)
#pragma unroll
        for (int r = 0; r < 4; ++r) {
            float s = 0.f;
#pragma unroll
            for (int ns = 0; ns < 4; ++ns) {
                float v = acc[ms][ns][r] + bv[ns];
                acc[ms][ns][r] = v;
                s += v * v;
            }
            ps[ms][r] = s;
        }
#pragma unroll
    for (int d = 1; d < 16; d <<= 1)
#pragma unroll
        for (int ms = 0; ms < 4; ++ms)
#pragma unroll
            for (int r = 0; r < 4; ++r) ps[ms][r] += __shfl_xor(ps[ms][r], d, 64);
    if ((lane & 15) == 0) {
#pragma unroll
        for (int ms = 0; ms < 4; ++ms)
#pragma unroll
            for (int r = 0; r < 4; ++r) ssl[wid][ms * 16 + (lane >> 4) * 4 + r] = ps[ms][r];
    }
    __syncthreads();
    // normalize + write x-tile to LDS (swizzled)
#pragma unroll
    for (int ms = 0; ms < 4; ++ms)
#pragma unroll
        for (int r = 0; r < 4; ++r) {
            int rt = ms * 16 + (lane >> 4) * 4 + r;
            float tot = ssl[0][rt] + ssl[1][rt] + ssl[2][rt] + ssl[3][rt];
            float inv = 1.0f / fmaxf(sqrtf(tot), 1e-12f);
            int sw = (rt & 7) << 3;
#pragma unroll
            for (int ns = 0; ns < 4; ++ns) {
                int col = wid * 64 + ns * 16 + (lane & 15);
                xt[(rt * 256 + col) ^ sw] = f2bf(acc[ms][ns][r] * inv);
            }
        }
    __syncthreads();

    // ---- stage 2: gemm2 K=256 -> N=128, A from LDS ----
    f32x4 acc2[4][2];
#pragma unroll
    for (int ms = 0; ms < 4; ++ms)
#pragma unroll
        for (int ns = 0; ns < 2; ++ns) acc2[ms][ns] = (f32x4){0.f, 0.f, 0.f, 0.f};
#pragma unroll
    for (int ks = 0; ks < 8; ++ks) {
        bf16x8 a2[4];
#pragma unroll
        for (int ms = 0; ms < 4; ++ms) {
            int rowA = ms * 16 + (lane & 15);
            int eb = (rowA * 256 + koff + ks * 32) ^ ((rowA & 7) << 3);
            a2[ms] = *reinterpret_cast<const bf16x8*>(&xt[eb]);
        }
#pragma unroll
        for (int ms = 0; ms < 4; ++ms)
#pragma unroll
            for (int ns = 0; ns < 2; ++ns)
                acc2[ms][ns] = __builtin_amdgcn_mfma_f32_16x16x32_bf16(a2[ms], b2f[ns][ks], acc2[ms][ns], 0, 0, 0);
    }
    // epilogue: scale rows by dsc, write bf16 gather table
#pragma unroll
    for (int ms = 0; ms < 4; ++ms)
#pragma unroll
        for (int r = 0; r < 4; ++r) {
            int row = m0 + ms * 16 + (lane >> 4) * 4 + r;
            if (row < M) {
                float sc = dsc[row];
#pragma unroll
                for (int ns = 0; ns < 2; ++ns)
                    out2[(size_t)row * 128 + wid * 32 + ns * 16 + (lane & 15)] =
                        f2bf(acc2[ms][ns][r] * sc);
            }
        }
}

// ---------------- launch ----------------

extern "C" void kernel_launch(void* const* d_in, const int* in_sizes, int n_in,
                              void* d_out, int out_size, void* d_ws, size_t ws_size,
                              hipStream_t stream) {
    const float* emb = (const float*)d_in[0];
    const float* W1 = (const float*)d_in[1];
    const float* b1 = (const float*)d_in[2];
    const float* W2 = (const float*)d_in[3];
    const float* b2 = (const float*)d_in[4];
    const int* eidx = (const int*)d_in[5];

    const int Nn = in_sizes[0] / 128;   // 100000
    const int E = in_sizes[5] / 2;      // 1600000
    const int* srcp = eidx;
    const int* dstp = eidx + E;

    float* ws = (float*)d_ws;
    size_t o = 0;
    uint* tbl1 = (uint*)(ws + o);  o += (size_t)Nn * 64;   // dis*emb bf16 [Nn][128]
    uint* axb = (uint*)(ws + o);   o += (size_t)Nn * 64;   // agg1 out bf16 [Nn][128]
    uint* tbl2 = (uint*)(ws + o);  o += (size_t)Nn * 64;   // dis*h2 bf16 [Nn][128]
    ushort* W1t = (ushort*)(ws + o); o += 128 * 256 / 2;   // [256][128]
    ushort* W2t = (ushort*)(ws + o); o += 256 * 128 / 2;   // [128][256]
    float* dis = ws + o;    o += Nn;
    int* cnt = (int*)(ws + o);    o += Nn;
    int* offs = (int*)(ws + o);   o += Nn + 16;
    int* bsum = (int*)(ws + o);   o += 128;
    int* rank = (int*)(ws + o);   o += E;
    int* rec = (int*)(ws + o);    o += E;

    int zb = (Nn + 255) / 256;                 // 391
    prep_kernel<<<zb + 256, 256, 0, stream>>>(W1, W1t, W2, W2t, cnt, Nn, zb);

    int EBc = (E + 255) / 256;                 // 1 edge/thread, max occupancy
    count_kernel<<<EBc, 256, 0, stream>>>(dstp, cnt, rank, E);

    int NB = (Nn + 1023) / 1024;               // 98
    scan_part<<<NB, 1024, 0, stream>>>(cnt, bsum, Nn);
    scan_top<<<1, 128, 0, stream>>>(bsum, NB);
    scan_final<<<NB, 1024, 0, stream>>>(cnt, bsum, offs, dis, Nn, E);

    int n4 = Nn * 128 / 4;
    int CB = 2048;
    int FB = (E + 511) / 512;                  // 2 edges/thread fill
    fill_cast_kernel<<<FB + CB, 256, 0, stream>>>(srcp, dstp, rank, offs, rec, E,
                                                  (const float4*)emb, dis, (ushort4*)tbl1, n4, FB, CB);

    int npb = (Nn + 31) / 32;                  // 3125 node-blocks per pass
    // layer 1: aggregate pre-scaled emb (bf16 out), then fused GEMM1+norm+GEMM2 (+dis scale)
    agg_sliced<false, true><<<8 * npb, 256, 0, stream>>>(tbl1, offs, rec, dis, nullptr, axb, Nn, npb);
    fused_gemm<<<(Nn + 63) / 64, 256, 0, stream>>>((const ushort*)axb, W1t, b1, W2t, dis, (ushort*)tbl2, Nn);

    // layer 2 aggregate + bias (fp32 out)
    agg_sliced<true, false><<<8 * npb, 256, 0, stream>>>(tbl2, offs, rec, dis, b2, d_out, Nn, npb);
}

// Round 9
// 301.425 us; speedup vs baseline: 1.8492x; 1.8492x over previous
//
#include <hip/hip_runtime.h>
#include <hip/hip_bf16.h>

typedef __attribute__((ext_vector_type(8))) short bf16x8;
typedef __attribute__((ext_vector_type(4))) float f32x4;

// ---------------- helpers ----------------

__device__ __forceinline__ ushort f2bf(float f) {
    unsigned int b = __float_as_uint(f);
    unsigned int r = (b + 0x7fffu + ((b >> 16) & 1u)) >> 16;  // RNE
    return (ushort)r;
}
__device__ __forceinline__ float bflo(uint v) { return __uint_as_float(v << 16); }
__device__ __forceinline__ float bfhi(uint v) { return __uint_as_float(v & 0xffff0000u); }

// ---------------- prep: zero cnt + transpose-cast both weights ----------------

__global__ __launch_bounds__(256) void prep_kernel(const float* __restrict__ W1, ushort* __restrict__ W1t,
                                                   const float* __restrict__ W2, ushort* __restrict__ W2t,
                                                   int* __restrict__ cnt, int Nn, int zb) {
    int b = blockIdx.x, t = threadIdx.x;
    if (b < zb) {
        int i = b * 256 + t;
        if (i < Nn) cnt[i] = 0;
    } else if (b < zb + 128) {
        int i = (b - zb) * 256 + t;            // W1t[n][k], n in [0,256), k in [0,128)
        int n = i >> 7, k = i & 127;
        W1t[i] = f2bf(W1[(size_t)k * 256 + n]);
    } else {
        int i = (b - zb - 128) * 256 + t;      // W2t[n][k], n in [0,128), k in [0,256)
        int n = i >> 8, k = i & 255;
        W2t[i] = f2bf(W2[(size_t)k * 128 + n]);
    }
}

// ---------------- CSR build ----------------

// 2 edges/thread @ 3125 blocks: full wave occupancy (grid > resident cap) + 2x atomic ILP
__global__ void count_kernel(const int* __restrict__ dst, int* __restrict__ cnt,
                             int* __restrict__ rank, int E) {
    int i = blockIdx.x * blockDim.x + threadIdx.x;
    int e = i * 2;
    if (e + 1 < E) {
        int d0 = dst[e], d1 = dst[e + 1];
        int r0 = atomicAdd(&cnt[d0], 1);
        int r1 = atomicAdd(&cnt[d1], 1);
        rank[e] = r0; rank[e + 1] = r1;
    } else if (e < E) {
        rank[e] = atomicAdd(&cnt[dst[e]], 1);
    }
}

__global__ __launch_bounds__(1024) void scan_part(const int* __restrict__ cnt,
                                                  int* __restrict__ bsum, int Nn) {
    int i = blockIdx.x * 1024 + threadIdx.x;
    int v = (i < Nn) ? cnt[i] : 0;
#pragma unroll
    for (int d = 1; d < 64; d <<= 1) v += __shfl_xor(v, d, 64);
    __shared__ int wsums[16];
    if ((threadIdx.x & 63) == 0) wsums[threadIdx.x >> 6] = v;
    __syncthreads();
    if (threadIdx.x == 0) {
        int s = 0;
        for (int w = 0; w < 16; ++w) s += wsums[w];
        bsum[blockIdx.x] = s;
    }
}

// parallel exclusive scan over NB<=128 block sums (1 block, 128 threads)
__global__ __launch_bounds__(128) void scan_top(int* __restrict__ bsum, int NB) {
    int i = threadIdx.x;
    int v = (i < NB) ? bsum[i] : 0;
    int x = v;
#pragma unroll
    for (int d = 1; d < 64; d <<= 1) {
        int y = __shfl_up(x, d, 64);
        if ((i & 63) >= d) x += y;
    }
    __shared__ int w0;
    if (i == 63) w0 = x;
    __syncthreads();
    if (i >= 64) x += w0;
    if (i < NB) bsum[i] = x - v;
}

__global__ __launch_bounds__(1024) void scan_final(const int* __restrict__ cnt,
                                                   const int* __restrict__ bpre,
                                                   int* __restrict__ offs,
                                                   float* __restrict__ dis, int Nn, int E) {
    int i = blockIdx.x * 1024 + threadIdx.x;
    int v = (i < Nn) ? cnt[i] : 0;
    int lane = threadIdx.x & 63, wid = threadIdx.x >> 6;
    int x = v;
#pragma unroll
    for (int d = 1; d < 64; d <<= 1) {
        int y = __shfl_up(x, d, 64);
        if (lane >= d) x += y;
    }
    __shared__ int wsum[16];
    __shared__ int wpre[16];
    if (lane == 63) wsum[wid] = x;
    __syncthreads();
    if (threadIdx.x == 0) {
        int run = 0;
        for (int w = 0; w < 16; ++w) { wpre[w] = run; run += wsum[w]; }
    }
    __syncthreads();
    int excl = x - v + wpre[wid] + bpre[blockIdx.x];
    if (i < Nn) {
        offs[i] = excl;
        dis[i] = rsqrtf((float)v + 1.0f);
    }
    if (blockIdx.x == 0 && threadIdx.x == 0) offs[Nn] = E;
}

// ---------------- fused fill (2-wide, atomic-free) + cast_scale ----------------
// blocks [0,FB): fill; [FB,FB+CB): tbl[s][c] = bf16(dis[s]*emb[s][c])

__global__ void fill_cast_kernel(const int* __restrict__ src, const int* __restrict__ dst,
                                 const int* __restrict__ rank, const int* __restrict__ offs,
                                 int* __restrict__ rec, int E,
                                 const float4* __restrict__ emb, const float* __restrict__ dis,
                                 ushort4* __restrict__ tbl, int n4, int FB, int CB) {
    if ((int)blockIdx.x < FB) {
        int i = blockIdx.x * 256 + threadIdx.x;
        int e = i * 2;
        if (e + 1 < E) {
            int d0 = dst[e], d1 = dst[e + 1];
            int s0 = src[e], s1 = src[e + 1];
            int r0 = rank[e], r1 = rank[e + 1];
            int o0 = offs[d0], o1 = offs[d1];
            rec[o0 + r0] = s0;
            rec[o1 + r1] = s1;
        } else if (e < E) {
            rec[offs[dst[e]] + rank[e]] = src[e];
        }
    } else {
        int stride = CB * 256;
        for (int i = ((int)blockIdx.x - FB) * 256 + (int)threadIdx.x; i < n4; i += stride) {
            float s = dis[i >> 5];
            float4 v = emb[i];
            ushort4 o;
            o.x = f2bf(v.x * s); o.y = f2bf(v.y * s); o.z = f2bf(v.z * s); o.w = f2bf(v.w * s);
            tbl[i] = o;
        }
    }
}

// ---------------- flat aggregation over 128 bf16 cols (pre-scaled table) ----------------
// tbl[s] = dis[s]*x[s] (bf16). out = dn * (tbl[gw] + sum_e tbl[rec[e]])  (+bias)
// one wave per node; lane owns cols {2*lane, 2*lane+1} packed in one uint.
// 16-wide edge batching: lanes 0-15 load 16 consecutive rec entries (one line),
// indices broadcast via __shfl; 16 independent 256B row-gathers in flight.

template <bool BIAS, bool BF16OUT>
__global__ __launch_bounds__(256) void agg_kernel(const uint* __restrict__ tbl,   // [Nn][64]
                                                  const int* __restrict__ offs,
                                                  const int* __restrict__ rec,    // src per edge
                                                  const float* __restrict__ dis,
                                                  const float* __restrict__ bias,
                                                  void* __restrict__ outp, int Nn) {
    int gw = (int)((blockIdx.x * 256 + threadIdx.x) >> 6);
    uint lane = threadIdx.x & 63;
    if (gw >= Nn) return;
    float dn = dis[gw];
    int e0 = offs[gw], e1 = offs[gw + 1];
    uint hv = tbl[(uint)gw * 64u + lane];
    float ax = bflo(hv), ay = bfhi(hv);

    for (int base = e0; base < e1; base += 16) {
        int ee = base + (int)(lane & 15u);
        uint rr = (uint)rec[ee < e1 ? ee : e1 - 1];
        uint vv[16];
#pragma unroll
        for (int j = 0; j < 16; ++j) {
            uint idx = (uint)__shfl((int)rr, j, 64);
            vv[j] = tbl[idx * 64u + lane];
        }
#pragma unroll
        for (int j = 0; j < 16; ++j) {
            uint v = (base + j < e1) ? vv[j] : 0u;
            ax += bflo(v);
            ay += bfhi(v);
        }
    }

    ax *= dn; ay *= dn;
    if (BIAS) {
        float2 bv = reinterpret_cast<const float2*>(bias)[lane];
        ax += bv.x; ay += bv.y;
    }
    if (BF16OUT) {
        reinterpret_cast<uint*>(outp)[(uint)gw * 64u + lane] =
            (uint)f2bf(ax) | ((uint)f2bf(ay) << 16);
    } else {
        float2 o; o.x = ax; o.y = ay;
        reinterpret_cast<float2*>(outp)[(uint)gw * 64u + lane] = o;
    }
}

// ---------------- fused MFMA GEMM: x = L2norm(A@W1 + b1); tbl2 = dis * (x@W2) ----------------
// A [M][128] bf16 (agg1 out), W1t [256][128] bf16, W2t [128][256] bf16.
// block = 4 waves, 64-row tile. All 32 stage-1 fragment loads hoisted (single
// latency window); W2 fragment loads issued under the stage-1 epilogue.
// __launch_bounds__(256,2): cap 256 VGPR so all fragments stay in flight.
// mfma_f32_16x16x32_bf16 C/D layout: col=lane&15, row=(lane>>4)*4+reg  [measured m89].

__global__ __launch_bounds__(256, 2) void fused_gemm(const ushort* __restrict__ A,
                                                     const ushort* __restrict__ W1t,
                                                     const float* __restrict__ bias1,
                                                     const ushort* __restrict__ W2t,
                                                     const float* __restrict__ dsc,
                                                     ushort* __restrict__ out2, int M) {
    __shared__ ushort xt[64 * 256];   // 32KB x-tile, elem ^= (row&7)<<3 swizzle
    __shared__ float ssl[4][64];
    int lane = threadIdx.x & 63, wid = threadIdx.x >> 6;
    int m0 = blockIdx.x * 64;
    int koff = (lane >> 4) * 8;

    // ---- stage 1: gemm1 K=128 -> N=256 ----
    bf16x8 a[4][4], b1f[4][4];
#pragma unroll
    for (int ms = 0; ms < 4; ++ms) {
        int r = m0 + ms * 16 + (lane & 15);
        if (r >= M) r = M - 1;
        const bf16x8* p = reinterpret_cast<const bf16x8*>(A + (size_t)r * 128 + koff);
#pragma unroll
        for (int ks = 0; ks < 4; ++ks) a[ms][ks] = p[ks * 4];
    }
#pragma unroll
    for (int ns = 0; ns < 4; ++ns) {
        int c = wid * 64 + ns * 16 + (lane & 15);
        const bf16x8* p = reinterpret_cast<const bf16x8*>(W1t + (size_t)c * 128 + koff);
#pragma unroll
        for (int ks = 0; ks < 4; ++ks) b1f[ns][ks] = p[ks * 4];
    }

    f32x4 acc[4][4];
#pragma unroll
    for (int ms = 0; ms < 4; ++ms)
#pragma unroll
        for (int ns = 0; ns < 4; ++ns) acc[ms][ns] = (f32x4){0.f, 0.f, 0.f, 0.f};
#pragma unroll
    for (int ks = 0; ks < 4; ++ks)
#pragma unroll
        for (int ms = 0; ms < 4; ++ms)
#pragma unroll
            for (int ns = 0; ns < 4; ++ns)
                acc[ms][ns] = __builtin_amdgcn_mfma_f32_16x16x32_bf16(a[ms][ks], b1f[ns][ks], acc[ms][ns], 0, 0, 0);

    // issue W2 fragment loads now: latency hides under the epilogue below
    bf16x8 b2f[2][8];
#pragma unroll
    for (int ns = 0; ns < 2; ++ns) {
        int c = wid * 32 + ns * 16 + (lane & 15);
        const bf16x8* p = reinterpret_cast<const bf16x8*>(W2t + (size_t)c * 256 + koff);
#pragma unroll
        for (int ks = 0; ks < 8; ++ks) b2f[ns][ks] = p[ks * 4];
    }

    // bias + row sum-of-squares
    float bv[4];
#pragma unroll
    for (int ns = 0; ns < 4; ++ns) bv[ns] = bias1[wid * 64 + ns * 16 + (lane & 15)];
    float ps[4][4];
#pragma unroll
    for (int ms = 0; ms < 4; ++ms)
#pragma unroll
        for (int r = 0; r < 4; ++r) {
            float s = 0.f;
#pragma unroll
            for (int ns = 0; ns < 4; ++ns) {
                float v = acc[ms][ns][r] + bv[ns];
                acc[ms][ns][r] = v;
                s += v * v;
            }
            ps[ms][r] = s;
        }
#pragma unroll
    for (int d = 1; d < 16; d <<= 1)
#pragma unroll
        for (int ms = 0; ms < 4; ++ms)
#pragma unroll
            for (int r = 0; r < 4; ++r) ps[ms][r] += __shfl_xor(ps[ms][r], d, 64);
    if ((lane & 15) == 0) {
#pragma unroll
        for (int ms = 0; ms < 4; ++ms)
#pragma unroll
            for (int r = 0; r < 4; ++r) ssl[wid][ms * 16 + (lane >> 4) * 4 + r] = ps[ms][r];
    }
    __syncthreads();
    // normalize + write x-tile to LDS (swizzled)
#pragma unroll
    for (int ms = 0; ms < 4; ++ms)
#pragma unroll
        for (int r = 0; r < 4; ++r) {
            int rt = ms * 16 + (lane >> 4) * 4 + r;
            float tot = ssl[0][rt] + ssl[1][rt] + ssl[2][rt] + ssl[3][rt];
            float inv = 1.0f / fmaxf(sqrtf(tot), 1e-12f);
            int sw = (rt & 7) << 3;
#pragma unroll
            for (int ns = 0; ns < 4; ++ns) {
                int col = wid * 64 + ns * 16 + (lane & 15);
                xt[(rt * 256 + col) ^ sw] = f2bf(acc[ms][ns][r] * inv);
            }
        }
    __syncthreads();

    // ---- stage 2: gemm2 K=256 -> N=128, A from LDS ----
    f32x4 acc2[4][2];
#pragma unroll
    for (int ms = 0; ms < 4; ++ms)
#pragma unroll
        for (int ns = 0; ns < 2; ++ns) acc2[ms][ns] = (f32x4){0.f, 0.f, 0.f, 0.f};
#pragma unroll
    for (int ks = 0; ks < 8; ++ks) {
        bf16x8 a2[4];
#pragma unroll
        for (int ms = 0; ms < 4; ++ms) {
            int rowA = ms * 16 + (lane & 15);
            int eb = (rowA * 256 + koff + ks * 32) ^ ((rowA & 7) << 3);
            a2[ms] = *reinterpret_cast<const bf16x8*>(&xt[eb]);
        }
#pragma unroll
        for (int ms = 0; ms < 4; ++ms)
#pragma unroll
            for (int ns = 0; ns < 2; ++ns)
                acc2[ms][ns] = __builtin_amdgcn_mfma_f32_16x16x32_bf16(a2[ms], b2f[ns][ks], acc2[ms][ns], 0, 0, 0);
    }
    // epilogue: scale rows by dsc, write bf16 gather table
#pragma unroll
    for (int ms = 0; ms < 4; ++ms)
#pragma unroll
        for (int r = 0; r < 4; ++r) {
            int row = m0 + ms * 16 + (lane >> 4) * 4 + r;
            if (row < M) {
                float sc = dsc[row];
#pragma unroll
                for (int ns = 0; ns < 2; ++ns)
                    out2[(size_t)row * 128 + wid * 32 + ns * 16 + (lane & 15)] =
                        f2bf(acc2[ms][ns][r] * sc);
            }
        }
}

// ---------------- launch ----------------

extern "C" void kernel_launch(void* const* d_in, const int* in_sizes, int n_in,
                              void* d_out, int out_size, void* d_ws, size_t ws_size,
                              hipStream_t stream) {
    const float* emb = (const float*)d_in[0];
    const float* W1 = (const float*)d_in[1];
    const float* b1 = (const float*)d_in[2];
    const float* W2 = (const float*)d_in[3];
    const float* b2 = (const float*)d_in[4];
    const int* eidx = (const int*)d_in[5];

    const int Nn = in_sizes[0] / 128;   // 100000
    const int E = in_sizes[5] / 2;      // 1600000
    const int* srcp = eidx;
    const int* dstp = eidx + E;

    float* ws = (float*)d_ws;
    size_t o = 0;
    uint* tbl1 = (uint*)(ws + o);  o += (size_t)Nn * 64;   // dis*emb bf16 [Nn][128]
    uint* axb = (uint*)(ws + o);   o += (size_t)Nn * 64;   // agg1 out bf16 [Nn][128]
    uint* tbl2 = (uint*)(ws + o);  o += (size_t)Nn * 64;   // dis*h2 bf16 [Nn][128]
    ushort* W1t = (ushort*)(ws + o); o += 128 * 256 / 2;   // [256][128]
    ushort* W2t = (ushort*)(ws + o); o += 256 * 128 / 2;   // [128][256]
    float* dis = ws + o;    o += Nn;
    int* cnt = (int*)(ws + o);    o += Nn;
    int* offs = (int*)(ws + o);   o += Nn + 16;
    int* bsum = (int*)(ws + o);   o += 128;
    int* rank = (int*)(ws + o);   o += E;
    int* rec = (int*)(ws + o);    o += E;

    int zb = (Nn + 255) / 256;                 // 391
    prep_kernel<<<zb + 256, 256, 0, stream>>>(W1, W1t, W2, W2t, cnt, Nn, zb);

    int EBc = (E + 511) / 512;                 // 2 edges/thread, 3125 blocks
    count_kernel<<<EBc, 256, 0, stream>>>(dstp, cnt, rank, E);

    int NB = (Nn + 1023) / 1024;               // 98
    scan_part<<<NB, 1024, 0, stream>>>(cnt, bsum, Nn);
    scan_top<<<1, 128, 0, stream>>>(bsum, NB);
    scan_final<<<NB, 1024, 0, stream>>>(cnt, bsum, offs, dis, Nn, E);

    int n4 = Nn * 128 / 4;
    int CB = 2048;
    int FB = (E + 511) / 512;                  // 2 edges/thread fill
    fill_cast_kernel<<<FB + CB, 256, 0, stream>>>(srcp, dstp, rank, offs, rec, E,
                                                  (const float4*)emb, dis, (ushort4*)tbl1, n4, FB, CB);

    // layer 1: aggregate pre-scaled emb (bf16 out), then fused GEMM1+norm+GEMM2 (+dis scale)
    agg_kernel<false, true><<<(Nn + 3) / 4, 256, 0, stream>>>(tbl1, offs, rec, dis, nullptr, axb, Nn);
    fused_gemm<<<(Nn + 63) / 64, 256, 0, stream>>>((const ushort*)axb, W1t, b1, W2t, dis, (ushort*)tbl2, Nn);

    // layer 2 aggregate + bias (fp32 out)
    agg_kernel<true, false><<<(Nn + 3) / 4, 256, 0, stream>>>(tbl2, offs, rec, dis, b2, d_out, Nn);
}